// Round 5
// baseline (468.844 us; speedup 1.0000x reference)
//
#include <hip/hip_runtime.h>

// Problem constants: B=16, S=2048, D=1024, P=8192, R=16, NL=64, span<=31
#define S_LEN      2048
#define D_DIM      1024
#define R_DIM      16
#define OUT_STRIDE 2064          // 2*D + R
#define NBUCK      8192          // (B*S)>>2 coarse sort buckets (32 KB LDS hist)
#define BPT        8             // buckets per thread in the scan (NBUCK/1024)
#define G          16            // sorted jobs per gather group (traffic ~ 2+31/G)
#define QW         256           // column quarter width (floats); 4 slices/group

// ---------------------------------------------------------------------------
// Fused counting sort of the 2P span-jobs by coarse start bucket
// ((b*S + s) >> 2). One workgroup, everything in LDS.
__global__ __launch_bounds__(1024) void sort_jobs(
    const int* __restrict__ bidx, const int* __restrict__ e1s,
    const int* __restrict__ e2s, int* __restrict__ sorted, int njobs)
{
    __shared__ int hist[NBUCK];   // 32 KB
    __shared__ int part[1024];    // 4 KB
    const int t = threadIdx.x;

#pragma unroll
    for (int i = 0; i < BPT; ++i) hist[t * BPT + i] = 0;
    __syncthreads();

    for (int j = t; j < njobs; j += 1024) {
        const int p = j >> 1;
        const int s = (j & 1) ? e2s[p] : e1s[p];
        atomicAdd(&hist[(bidx[p] * S_LEN + s) >> 2], 1);
    }
    __syncthreads();

    int v[BPT];
    int sum = 0;
#pragma unroll
    for (int i = 0; i < BPT; ++i) { v[i] = hist[t * BPT + i]; sum += v[i]; }
    part[t] = sum;
    __syncthreads();
    for (int off = 1; off < 1024; off <<= 1) {
        int x = (t >= off) ? part[t - off] : 0;
        __syncthreads();
        part[t] += x;
        __syncthreads();
    }
    int run = (t == 0) ? 0 : part[t - 1];
#pragma unroll
    for (int i = 0; i < BPT; ++i) { int c = v[i]; hist[t * BPT + i] = run; run += c; }
    __syncthreads();

    for (int j = t; j < njobs; j += 1024) {
        const int p = j >> 1;
        const int s = (j & 1) ? e2s[p] : e1s[p];
        const int pos = atomicAdd(&hist[(bidx[p] * S_LEN + s) >> 2], 1);
        sorted[pos] = j;
    }
}

// ---------------------------------------------------------------------------
// Grouped gather v8: G=16 traffic reduction (L1 demand ~256 MB vs 570 MB at
// G=4) COMBINED WITH v4-style concurrency. Evidence v3-v7: time tracks
// occupancy inversely (63%->82us, 32%->85, 20%->112); the machine is
// latency-hiding-bound, not supply-bound, and every barrier-synced/LDS
// structure traded away resident waves. So: single-wave 64-thread blocks,
// no LDS, no barriers, quarter-width col slices -> 4096 independent blocks
// (~16/CU schedulable). Per 4-row chunk: 4 independent dwordx4 loads then
// 512 cycles of FMA (16 jobs x 4 rows x 4 comps) -- compute covers L2/L3
// latency at 3-4 waves/SIMD even with a collapsed load pipeline. Weights
// are wave-uniform scalar selects (js/len/w in SGPRs, one SGPR operand per
// v_fmac); out-of-window rows weight 0; tail rows clamped. Output metadata
// recomputed in the epilogue (sorted[] re-read, L2 hit) to keep main-loop
// SGPR pressure at ~48 and avoid spill.
__global__ __launch_bounds__(64, 4) void gather_g16q(
    const float* __restrict__ tok,     // [B*S, D] fp32
    const int*   __restrict__ sorted,  // [2P] sorted job ids
    const int*   __restrict__ bidx,
    const int*   __restrict__ e1s, const int* __restrict__ e1e,
    const int*   __restrict__ e2s, const int* __restrict__ e2e,
    const int*   __restrict__ ridx,
    const float* __restrict__ rtab,    // [NL, R]
    float*       __restrict__ out)     // [P, 2D+R]
{
    const int blk = blockIdx.x;
    // XCD swizzle: contiguous work ranges per XCD (grid 4096, %8==0, bijective)
    const int w  = (blk & 7) * (gridDim.x >> 3) + (blk >> 3);
    const int g  = w >> 2;             // job group (16 sorted jobs)
    const int ch = w & 3;              // col quarter: floats [ch*256, ch*256+256)
    const int ln = threadIdx.x;        // 0..63, 4 cols each

    // group metadata -> SGPRs: start, length, 1/length (48 scalar regs)
    int   js[G], jlen[G];
    float jw[G];
    int mins = 0x7fffffff, maxe = 0;
#pragma unroll
    for (int i = 0; i < G; ++i) {
        const int id = __builtin_amdgcn_readfirstlane(sorted[g * G + i]);
        const int p  = id >> 1;
        const int h  = id & 1;
        const int b  = __builtin_amdgcn_readfirstlane(bidx[p]);
        const int s  = __builtin_amdgcn_readfirstlane(h ? e2s[p] : e1s[p]);
        const int e  = __builtin_amdgcn_readfirstlane(h ? e2e[p] : e1e[p]);
        js[i]   = b * S_LEN + s;
        jlen[i] = e - s;
        jw[i]   = 1.0f / (float)(e - s);
        mins = min(mins, js[i]);
        maxe = max(maxe, b * S_LEN + e);
    }

    const int nrows = maxe - mins;             // >= 1
    const int rmax  = nrows - 1;
    const int niter = (nrows + 3) >> 2;

    // row stride = D/4 = 256 float4; lane's col = ch*256 + ln*4
    const float4* base = reinterpret_cast<const float4*>(tok) +
                         (size_t)mins * (D_DIM / 4) + ch * (QW / 4) + ln;

    float4 acc[G];
#pragma unroll
    for (int i = 0; i < G; ++i) acc[i] = make_float4(0.f, 0.f, 0.f, 0.f);

    for (int it = 0; it < niter; ++it) {
        const int r0 = it * 4;
        float4 cur[4];                          // 4 independent loads in flight
#pragma unroll
        for (int k = 0; k < 4; ++k)
            cur[k] = base[(size_t)min(r0 + k, rmax) * (D_DIM / 4)];

        const int gr = mins + r0;
#pragma unroll
        for (int i = 0; i < G; ++i) {           // wave-uniform scalar weights
            const float w0 = ((unsigned)(gr + 0 - js[i]) < (unsigned)jlen[i]) ? jw[i] : 0.f;
            const float w1 = ((unsigned)(gr + 1 - js[i]) < (unsigned)jlen[i]) ? jw[i] : 0.f;
            const float w2 = ((unsigned)(gr + 2 - js[i]) < (unsigned)jlen[i]) ? jw[i] : 0.f;
            const float w3 = ((unsigned)(gr + 3 - js[i]) < (unsigned)jlen[i]) ? jw[i] : 0.f;
            acc[i].x += cur[0].x * w0 + cur[1].x * w1 + cur[2].x * w2 + cur[3].x * w3;
            acc[i].y += cur[0].y * w0 + cur[1].y * w1 + cur[2].y * w2 + cur[3].y * w3;
            acc[i].z += cur[0].z * w0 + cur[1].z * w1 + cur[2].z * w2 + cur[3].z * w3;
            acc[i].w += cur[0].w * w0 + cur[1].w * w1 + cur[2].w * w2 + cur[3].w * w3;
        }
    }

    // epilogue: recompute output metadata (cheap L2 re-reads, saves SGPRs)
#pragma unroll
    for (int i = 0; i < G; ++i) {
        const int id = __builtin_amdgcn_readfirstlane(sorted[g * G + i]);
        const int p  = id >> 1;
        const int h  = id & 1;
        float* dst = out + (size_t)p * OUT_STRIDE + h * D_DIM + ch * QW + ln * 4;
        *reinterpret_cast<float4*>(dst) = acc[i];
        if (ch == 0 && h == 0 && ln < 4) {      // rel row once per pair
            const float4 rv = *reinterpret_cast<const float4*>(
                rtab + ridx[p] * R_DIM + ln * 4);
            *reinterpret_cast<float4*>(
                out + (size_t)p * OUT_STRIDE + 2 * D_DIM + ln * 4) = rv;
        }
    }
}

// ---------------------------------------------------------------------------
extern "C" void kernel_launch(void* const* d_in, const int* in_sizes, int n_in,
                              void* d_out, int out_size, void* d_ws, size_t ws_size,
                              hipStream_t stream) {
    const float* tok  = (const float*)d_in[0];
    const int*   bidx = (const int*)d_in[1];
    const int*   e1s  = (const int*)d_in[2];
    const int*   e1e  = (const int*)d_in[3];
    const int*   e2s  = (const int*)d_in[4];
    const int*   e2e  = (const int*)d_in[5];
    const int*   ridx = (const int*)d_in[6];
    const float* rtab = (const float*)d_in[7];
    float*       out  = (float*)d_out;

    const int P     = in_sizes[1];   // 8192
    const int njobs = 2 * P;         // 16384

    int* sorted = (int*)d_ws;        // njobs ints

    sort_jobs<<<1, 1024, 0, stream>>>(bidx, e1s, e2s, sorted, njobs);

    const int nblocks = (njobs / G) * 4;        // 4 col-quarters per group
    gather_g16q<<<nblocks, 64, 0, stream>>>(
        tok, sorted, bidx, e1s, e1e, e2s, e2e, ridx, rtab, out);
}

// Round 6
// 288.926 us; speedup vs baseline: 1.6227x; 1.6227x over previous
//
#include <hip/hip_runtime.h>

// Problem constants: B=16, S=2048, D=1024, P=8192, R=16, NL=64, span<=31
#define S_LEN      2048
#define D_DIM      1024
#define R_DIM      16
#define OUT_STRIDE 2064          // 2*D + R
#define NBUCK      8192          // (B*S)>>2 coarse sort buckets (32 KB LDS hist)
#define BPT        8             // buckets per thread in the scan (NBUCK/1024)
#define G          16            // sorted jobs per gather group
#define NSL        8             // column slices per group (128 floats each)
#define SLW        128           // slice width in floats

// ---------------------------------------------------------------------------
// Fused counting sort of the 2P span-jobs by coarse start bucket
// ((b*S + s) >> 2). One workgroup, everything in LDS.
__global__ __launch_bounds__(1024) void sort_jobs(
    const int* __restrict__ bidx, const int* __restrict__ e1s,
    const int* __restrict__ e2s, int* __restrict__ sorted, int njobs)
{
    __shared__ int hist[NBUCK];   // 32 KB
    __shared__ int part[1024];    // 4 KB
    const int t = threadIdx.x;

#pragma unroll
    for (int i = 0; i < BPT; ++i) hist[t * BPT + i] = 0;
    __syncthreads();

    for (int j = t; j < njobs; j += 1024) {
        const int p = j >> 1;
        const int s = (j & 1) ? e2s[p] : e1s[p];
        atomicAdd(&hist[(bidx[p] * S_LEN + s) >> 2], 1);
    }
    __syncthreads();

    int v[BPT];
    int sum = 0;
#pragma unroll
    for (int i = 0; i < BPT; ++i) { v[i] = hist[t * BPT + i]; sum += v[i]; }
    part[t] = sum;
    __syncthreads();
    for (int off = 1; off < 1024; off <<= 1) {
        int x = (t >= off) ? part[t - off] : 0;
        __syncthreads();
        part[t] += x;
        __syncthreads();
    }
    int run = (t == 0) ? 0 : part[t - 1];
#pragma unroll
    for (int i = 0; i < BPT; ++i) { int c = v[i]; hist[t * BPT + i] = run; run += c; }
    __syncthreads();

    for (int j = t; j < njobs; j += 1024) {
        const int p = j >> 1;
        const int s = (j & 1) ? e2s[p] : e1s[p];
        const int pos = atomicAdd(&hist[(bidx[p] * S_LEN + s) >> 2], 1);
        sorted[pos] = j;
    }
}

// ---------------------------------------------------------------------------
// Grouped gather v9: G=16 traffic (observed FETCH 109 MB, window traffic
// ~270 MB vs 655 MB at G=4) at v4-level request pressure. Evidence: v4/v5
// both saturate ~8 TB/s L1-side supply; time = window_traffic / 8 TB/s when
// occupancy holds. v7 (20% occ, barriers) and v8 (VGPR=64 clamp -> 850 MB
// accumulator spill, WRITE 607 MB) lost the G=16 payoff to structure.
// Here: float2 per lane -> acc[16] = 32 VGPRs (not 64); single-wave
// 64-thread blocks, NO LDS, NO barriers; 8 col-slices of 128 floats ->
// 8192 independent blocks (32 waves/CU, fine tail granularity). Data regs
// acc32+cur8+nxt8=48, total ~60 -> no spill even at a 64-VGPR allocation;
// launch_bounds(64,6) caps at ~85 so the cur/nxt prefetch rotation can
// survive. Weights are wave-uniform scalar selects feeding v_fmac (SGPR
// operand); out-of-window rows weight 0; tail rows clamped.
__global__ __launch_bounds__(64, 6) void gather_g16f2(
    const float* __restrict__ tok,     // [B*S, D] fp32
    const int*   __restrict__ sorted,  // [2P] sorted job ids
    const int*   __restrict__ bidx,
    const int*   __restrict__ e1s, const int* __restrict__ e1e,
    const int*   __restrict__ e2s, const int* __restrict__ e2e,
    const int*   __restrict__ ridx,
    const float* __restrict__ rtab,    // [NL, R]
    float*       __restrict__ out)     // [P, 2D+R]
{
    const int blk = blockIdx.x;
    // XCD swizzle: contiguous work ranges per XCD (grid 8192, %8==0, bijective)
    const int w  = (blk & 7) * (gridDim.x >> 3) + (blk >> 3);
    const int g  = w >> 3;             // job group (16 sorted jobs)
    const int sl = w & 7;              // col slice: floats [sl*128, sl*128+128)
    const int ln = threadIdx.x;        // 0..63, 2 cols each

    // group metadata -> SGPRs: start, length, 1/length
    int   js[G], jlen[G];
    float jw[G];
    int mins = 0x7fffffff, maxe = 0;
#pragma unroll
    for (int i = 0; i < G; ++i) {
        const int id = __builtin_amdgcn_readfirstlane(sorted[g * G + i]);
        const int p  = id >> 1;
        const int h  = id & 1;
        const int b  = __builtin_amdgcn_readfirstlane(bidx[p]);
        const int s  = __builtin_amdgcn_readfirstlane(h ? e2s[p] : e1s[p]);
        const int e  = __builtin_amdgcn_readfirstlane(h ? e2e[p] : e1e[p]);
        js[i]   = b * S_LEN + s;
        jlen[i] = e - s;
        jw[i]   = 1.0f / (float)(e - s);
        mins = min(mins, js[i]);
        maxe = max(maxe, b * S_LEN + e);
    }

    const int nrows = maxe - mins;             // >= 1
    const int rmax  = nrows - 1;
    const int niter = (nrows + 3) >> 2;

    // float2 row stride = D/2 = 512; lane's col = sl*128 + ln*2
    const float2* base = reinterpret_cast<const float2*>(tok) +
                         (size_t)mins * (D_DIM / 2) + sl * (SLW / 2) + ln;

    float2 acc[G];
#pragma unroll
    for (int i = 0; i < G; ++i) acc[i] = make_float2(0.f, 0.f);

    float2 cur[4];
#pragma unroll
    for (int k = 0; k < 4; ++k)
        cur[k] = base[(size_t)min(k, rmax) * (D_DIM / 2)];

    for (int it = 0; it < niter; ++it) {
        const int r0 = it * 4;
        float2 nxt[4];                          // next 4 rows (clamped)
#pragma unroll
        for (int k = 0; k < 4; ++k)
            nxt[k] = base[(size_t)min(r0 + 4 + k, rmax) * (D_DIM / 2)];

        const int gr = mins + r0;
#pragma unroll
        for (int i = 0; i < G; ++i) {           // wave-uniform scalar weights
            const float w0 = ((unsigned)(gr + 0 - js[i]) < (unsigned)jlen[i]) ? jw[i] : 0.f;
            const float w1 = ((unsigned)(gr + 1 - js[i]) < (unsigned)jlen[i]) ? jw[i] : 0.f;
            const float w2 = ((unsigned)(gr + 2 - js[i]) < (unsigned)jlen[i]) ? jw[i] : 0.f;
            const float w3 = ((unsigned)(gr + 3 - js[i]) < (unsigned)jlen[i]) ? jw[i] : 0.f;
            acc[i].x += cur[0].x * w0 + cur[1].x * w1 + cur[2].x * w2 + cur[3].x * w3;
            acc[i].y += cur[0].y * w0 + cur[1].y * w1 + cur[2].y * w2 + cur[3].y * w3;
        }
#pragma unroll
        for (int k = 0; k < 4; ++k) cur[k] = nxt[k];
    }

    // epilogue: recompute output metadata (scalar L2 re-reads, saves regs)
#pragma unroll
    for (int i = 0; i < G; ++i) {
        const int id = __builtin_amdgcn_readfirstlane(sorted[g * G + i]);
        const int p  = id >> 1;
        const int h  = id & 1;
        float* dst = out + (size_t)p * OUT_STRIDE + h * D_DIM + sl * SLW + ln * 2;
        *reinterpret_cast<float2*>(dst) = acc[i];
        if (sl == 0 && h == 0 && ln < 8) {      // rel row once per pair
            const float2 rv = *reinterpret_cast<const float2*>(
                rtab + ridx[p] * R_DIM + ln * 2);
            *reinterpret_cast<float2*>(
                out + (size_t)p * OUT_STRIDE + 2 * D_DIM + ln * 2) = rv;
        }
    }
}

// ---------------------------------------------------------------------------
extern "C" void kernel_launch(void* const* d_in, const int* in_sizes, int n_in,
                              void* d_out, int out_size, void* d_ws, size_t ws_size,
                              hipStream_t stream) {
    const float* tok  = (const float*)d_in[0];
    const int*   bidx = (const int*)d_in[1];
    const int*   e1s  = (const int*)d_in[2];
    const int*   e1e  = (const int*)d_in[3];
    const int*   e2s  = (const int*)d_in[4];
    const int*   e2e  = (const int*)d_in[5];
    const int*   ridx = (const int*)d_in[6];
    const float* rtab = (const float*)d_in[7];
    float*       out  = (float*)d_out;

    const int P     = in_sizes[1];   // 8192
    const int njobs = 2 * P;         // 16384

    int* sorted = (int*)d_ws;        // njobs ints

    sort_jobs<<<1, 1024, 0, stream>>>(bidx, e1s, e2s, sorted, njobs);

    const int nblocks = (njobs / G) * NSL;      // 1024 groups x 8 slices = 8192
    gather_g16f2<<<nblocks, 64, 0, stream>>>(
        tok, sorted, bidx, e1s, e1e, e2s, e2e, ridx, rtab, out);
}